// Round 7
// baseline (630.597 us; speedup 1.0000x reference)
//
#include <hip/hip_runtime.h>

typedef _Float16 f16;
typedef _Float16 f16x8 __attribute__((ext_vector_type(8)));
typedef _Float16 f16x4 __attribute__((ext_vector_type(4)));
typedef float    f32x4 __attribute__((ext_vector_type(4)));

#define GLD16(g, l)                                                            \
  __builtin_amdgcn_global_load_lds(                                            \
      (const __attribute__((address_space(1))) void*)(g),                      \
      (__attribute__((address_space(3))) void*)(l), 16, 0, 0)

static constexpr int S = 4096, H = 2048, B = 2;

// ------------------------------------------- single fused cast: hs | Wq|Wk|Wv
__global__ __launch_bounds__(256) void cast_all(
    const float* __restrict__ hs, const float* __restrict__ w0,
    const float* __restrict__ w1, const float* __restrict__ w2,
    f16* __restrict__ hs_h, f16* __restrict__ w_h) {
  const int hsN4 = B * S * H / 4;  // float4 groups in hs
  const int wN4  = H * H / 4;     // float4 groups per weight
  int i = blockIdx.x * 256 + threadIdx.x;
  float4 f;
  if (i < hsN4) {
    f = reinterpret_cast<const float4*>(hs)[i];
    f16x4 h = {(f16)f.x, (f16)f.y, (f16)f.z, (f16)f.w};
    reinterpret_cast<f16x4*>(hs_h)[i] = h;
  } else {
    int j = i - hsN4;
    int seg = j / wN4, off = j - seg * wN4;
    const float* src = seg == 0 ? w0 : (seg == 1 ? w1 : w2);
    f = reinterpret_cast<const float4*>(src)[off];
    f16x4 h = {(f16)f.x, (f16)f.y, (f16)f.z, (f16)f.w};
    reinterpret_cast<f16x4*>(w_h)[j] = h;
  }
}

// ---------------------------------------------------------------- TN GEMM
// C[m,n] = sum_k A[m,k]*B[n,k].
// BM=BN=256, BK=64, 512 threads = 8 waves (2M x 4N), per-wave 128x64 output
// as 8x4 fragments of 16x16x32 MFMA (acc[8][4] f32x4 = 128 regs).
// STAGING (this round): half-tile ring of FIVE 32KB buffers (160KB LDS).
//   half h = 128 M-rows of A (16KB) + 128 N-rows of B (16KB) for K-tile h>>1,
//   parity h&1 selects row-half, buffer = h % 5.
//   Tile t computes halves 2t,2t+1; stages half 2t+3 (A in ph0, B in ph1)
//   and half 2t+4 (A in ph2, B in ph3) -- 2 GLD per phase (spread, no burst).
//   Trailing wait per tile: vmcnt(4) -- retires half 2t+3 (2-3 phases of
//   cover) while half 2t+4's 4 loads stay in flight ACROSS the tile boundary
//   (T4 counted wait; never drains to 0 in steady state).
// Phases (m201 two-barrier skeleton, from r6): ph0 reads B-all (8 b128,
//   register-carried) + A-slab {0,1}; ph p reads A-slab {2p,2p+1};
//   [ph0: lgkmcnt(8)]; barrier; lgkmcnt(0); sched_barrier; setprio(1);
//   16 MFMA; setprio(0); [ph3: vmcnt(4)]; barrier.
// LDS swizzle (proven conflict-free r6): chunk (row,kc) at line-slot
//   kc ^ (row&7) ^ ((row&16)>>2); read uses same XOR (row bits 0-4 are
//   half-local, so the formula is unchanged within a half).
// MODE 0: fused QKV.  n<2048 -> Q(+bq) f16; <4096 -> K(+bk); else Vt[b][h][s](+bv)
// MODE 2: scores, batched. f16 out = v*scale + mask[b][n]
// MODE 3: PV, batched. f32 out.
template <int MODE>
__global__ __launch_bounds__(512, 2) void gemm_tn(
    const f16* __restrict__ A, const f16* __restrict__ Bm,
    void* __restrict__ C0, void* __restrict__ C1, void* __restrict__ C2,
    const float* __restrict__ x0, const float* __restrict__ x1,
    const float* __restrict__ x2, float scale, int K, int lda, int ldb) {
  __shared__ __attribute__((aligned(16))) char smem[163840];

  const int tileM = blockIdx.y * 256;
  const int tileN = blockIdx.x * 256;

  const int tid  = threadIdx.x;
  const int wave = tid >> 6, lane = tid & 63;
  const int wm = (wave >> 2) * 128;  // 0,128
  const int wn = (wave & 3) * 64;    // 0,64,128,192
  const int ln = lane & 15, kq = lane >> 4;

  f32x4 acc[8][4] = {};

  // batch-aware operand row bases (tiles never straddle batches: S%256==0)
  size_t rowB = tileN;
  if (MODE == 2) rowB = (size_t)(tileM >> 12) * S + tileN;  // Kh row = b*S + k
  if (MODE == 3) rowB = (size_t)(tileM >> 12) * H + tileN;  // Vt row = b*H + h
  const f16* gA = A + (size_t)tileM * lda;
  const f16* gB = Bm + rowB * ldb;

  // local (within-half) staging offsets: 128 rows x 8 chunks = 2 GLD rounds
  int aoffL[2], boffL[2], loffL[2];
#pragma unroll
  for (int j = 0; j < 2; ++j) {
    int id = j * 512 + tid;          // 0..1023
    int r = id >> 3;                 // local row 0..127
    int cs = (id & 7) ^ (r & 7) ^ ((r & 16) >> 2);
    aoffL[j] = r * lda + cs * 8;
    boffL[j] = r * ldb + cs * 8;
    loffL[j] = id * 8;               // f16 units within a 16KB half
  }

  const int nt = K >> 6;

  auto stageA = [&](int h, int buf) {
    f16* d = (f16*)(smem + buf * 32768);
    const f16* s = gA + (size_t)((h & 1) * 128) * lda + (size_t)(h >> 1) * 64;
#pragma unroll
    for (int j = 0; j < 2; ++j) GLD16(s + aoffL[j], d + loffL[j]);
  };
  auto stageB = [&](int h, int buf) {
    f16* d = (f16*)(smem + buf * 32768 + 16384);
    const f16* s = gB + (size_t)((h & 1) * 128) * ldb + (size_t)(h >> 1) * 64;
#pragma unroll
    for (int j = 0; j < 2; ++j) GLD16(s + boffL[j], d + loffL[j]);
  };

  // fragment read within a 128-row half (row bits 0-4 are half-local)
  auto rdfrag = [&](const f16* base, int rloc, int ks) -> f16x8 {
    const int row = rloc + ln;
    const int slot = (ks * 4 + kq) ^ (row & 7) ^ ((row & 16) >> 2);
    return *reinterpret_cast<const f16x8*>(&base[row * 64 + slot * 8]);
  };

  // ---- prologue: halves 0,1,2 -> buffers 0,1,2 (12 GLD/wave)
  stageA(0, 0); stageB(0, 0);
  stageA(1, 1); stageB(1, 1);
  stageA(2, 2); stageB(2, 2);
  asm volatile("s_waitcnt vmcnt(4)" ::: "memory");  // halves 0,1 done
  __builtin_amdgcn_s_barrier();

  const int ahalf = wm >> 7, bhalf = wn >> 7;
  int c0 = 0;  // (2t) % 5
  for (int t = 0; t < nt; ++t) {
    int bA = c0 + ahalf; if (bA >= 5) bA -= 5;
    int bB = c0 + bhalf; if (bB >= 5) bB -= 5;
    const f16* sAw = (const f16*)(smem + bA * 32768);
    const f16* sBw = (const f16*)(smem + bB * 32768 + 16384);
    int s3 = c0 + 3; if (s3 >= 5) s3 -= 5;
    int s4 = c0 + 4; if (s4 >= 5) s4 -= 5;
    const int h3 = 2 * t + 3, h4 = 2 * t + 4;
    const bool pf3 = h3 < 2 * nt, pf4 = h4 < 2 * nt;

    f16x8 bf[2][4];  // register-carried across the whole K-tile

#pragma unroll
    for (int p = 0; p < 4; ++p) {
      if (p == 0) {
#pragma unroll
        for (int ks = 0; ks < 2; ++ks)
#pragma unroll
          for (int y = 0; y < 4; ++y)
            bf[ks][y] = rdfrag(sBw, (wn & 64) + y * 16, ks);
      }
      f16x8 a00 = rdfrag(sAw, (2 * p + 0) * 16, 0);
      f16x8 a01 = rdfrag(sAw, (2 * p + 0) * 16, 1);
      f16x8 a10 = rdfrag(sAw, (2 * p + 1) * 16, 0);
      f16x8 a11 = rdfrag(sAw, (2 * p + 1) * 16, 1);
      // staging spread: 2 GLD per phase
      if (p == 0 && pf3) stageA(h3, s3);
      if (p == 1 && pf3) stageB(h3, s3);
      if (p == 2 && pf4) stageA(h4, s4);
      if (p == 3 && pf4) stageB(h4, s4);
      if (p == 0) asm volatile("s_waitcnt lgkmcnt(8)" ::: "memory");
      __builtin_amdgcn_s_barrier();
      asm volatile("s_waitcnt lgkmcnt(0)" ::: "memory");
      __builtin_amdgcn_sched_barrier(0);
      __builtin_amdgcn_s_setprio(1);
#pragma unroll
      for (int y = 0; y < 4; ++y) {
        acc[2 * p + 0][y] = __builtin_amdgcn_mfma_f32_16x16x32_f16(a00, bf[0][y], acc[2 * p + 0][y], 0, 0, 0);
        acc[2 * p + 1][y] = __builtin_amdgcn_mfma_f32_16x16x32_f16(a10, bf[0][y], acc[2 * p + 1][y], 0, 0, 0);
      }
#pragma unroll
      for (int y = 0; y < 4; ++y) {
        acc[2 * p + 0][y] = __builtin_amdgcn_mfma_f32_16x16x32_f16(a01, bf[1][y], acc[2 * p + 0][y], 0, 0, 0);
        acc[2 * p + 1][y] = __builtin_amdgcn_mfma_f32_16x16x32_f16(a11, bf[1][y], acc[2 * p + 1][y], 0, 0, 0);
      }
      __builtin_amdgcn_s_setprio(0);
      if (p == 3) {  // counted wait: retire half h3, keep h4 in flight
        if (pf4) asm volatile("s_waitcnt vmcnt(4)" ::: "memory");
        else     asm volatile("s_waitcnt vmcnt(0)" ::: "memory");
      }
      __builtin_amdgcn_s_barrier();
    }
    c0 += 2; if (c0 >= 5) c0 -= 5;
  }

  // ---- V epilogue (MODE 0, seg==2): LDS transpose, four 64-col passes
  if (MODE == 0 && (tileN >> 11) == 2) {
    const int nn0 = tileN - 2 * H;
    const int b = tileM >> 12, s0 = tileM & (S - 1);
    f16* sT = (f16*)smem;  // [col 0..63][row 0..255], stride 264 (33792 B)
#pragma unroll
    for (int p = 0; p < 4; ++p) {
      if ((wave & 3) == p) {
#pragma unroll
        for (int x = 0; x < 8; ++x)
#pragma unroll
          for (int y = 0; y < 4; ++y) {
            int scol = y * 16 + ln;
            float bias = x2[nn0 + p * 64 + scol];
            int row0 = wm + x * 16 + kq * 4;
            f16x4 h4 = {(f16)(acc[x][y][0] + bias), (f16)(acc[x][y][1] + bias),
                        (f16)(acc[x][y][2] + bias), (f16)(acc[x][y][3] + bias)};
            *reinterpret_cast<f16x4*>(&sT[scol * 264 + row0]) = h4;
          }
      }
      __syncthreads();
      {
        int c = tid >> 3, hh = tid & 7;
        const f16* src = &sT[c * 264 + hh * 32];
        f16* dst = (f16*)C2 + (size_t)b * H * S + (size_t)(nn0 + p * 64 + c) * S +
                   s0 + hh * 32;
#pragma unroll
        for (int j = 0; j < 4; ++j)
          reinterpret_cast<f16x8*>(dst)[j] = reinterpret_cast<const f16x8*>(src)[j];
      }
      __syncthreads();
    }
    return;
  }

#pragma unroll
  for (int x = 0; x < 8; ++x)
#pragma unroll
    for (int y = 0; y < 4; ++y)
#pragma unroll
      for (int r = 0; r < 4; ++r) {
        int m = tileM + wm + x * 16 + kq * 4 + r;
        int n = tileN + wn + y * 16 + ln;
        float v = acc[x][y][r];
        if (MODE == 0) {
          int seg = n >> 11, nn = n & 2047;  // seg 0/1 only (V handled above)
          if (seg == 0) {
            ((f16*)C0)[(size_t)m * H + nn] = (f16)(v + x0[nn]);
          } else {
            ((f16*)C1)[(size_t)m * H + nn] = (f16)(v + x1[nn]);
          }
        } else if (MODE == 2) {
          int b = m >> 12;
          ((f16*)C0)[(size_t)m * S + n] = (f16)(v * scale + x0[(size_t)b * S + n]);
        } else {
          ((float*)C0)[(size_t)m * H + n] = v;
        }
      }
}

// ------------------------------------------------- softmax over 4096 f16, in place
__global__ __launch_bounds__(256) void softmax_f16(f16* __restrict__ sc) {
  const int tid = threadIdx.x;
  f16* rp = sc + (size_t)blockIdx.x * S;
  f16x8 h[2];
#pragma unroll
  for (int j = 0; j < 2; ++j) h[j] = reinterpret_cast<f16x8*>(rp)[tid + j * 256];

  float v[16];
#pragma unroll
  for (int j = 0; j < 2; ++j)
#pragma unroll
    for (int e = 0; e < 8; ++e) v[j * 8 + e] = (float)h[j][e];

  float m = -1e30f;
#pragma unroll
  for (int e = 0; e < 16; ++e) m = fmaxf(m, v[e]);
#pragma unroll
  for (int off = 32; off; off >>= 1) m = fmaxf(m, __shfl_xor(m, off));

  __shared__ float red[8];
  int wave = tid >> 6, lane = tid & 63;
  if (lane == 0) red[wave] = m;
  __syncthreads();
  m = fmaxf(fmaxf(red[0], red[1]), fmaxf(red[2], red[3]));

  float s = 0.f;
#pragma unroll
  for (int e = 0; e < 16; ++e) { v[e] = __expf(v[e] - m); s += v[e]; }
#pragma unroll
  for (int off = 32; off; off >>= 1) s += __shfl_xor(s, off);
  if (lane == 0) red[4 + wave] = s;
  __syncthreads();
  s = red[4] + red[5] + red[6] + red[7];
  float inv = 1.0f / s;

#pragma unroll
  for (int j = 0; j < 2; ++j) {
#pragma unroll
    for (int e = 0; e < 8; ++e) h[j][e] = (f16)(v[j * 8 + e] * inv);
    reinterpret_cast<f16x8*>(rp)[tid + j * 256] = h[j];
  }
}

// ---------------------------------------------------------------- launch
extern "C" void kernel_launch(void* const* d_in, const int* in_sizes, int n_in,
                              void* d_out, int out_size, void* d_ws, size_t ws_size,
                              hipStream_t stream) {
  const float* hs   = (const float*)d_in[0];
  const float* mask = (const float*)d_in[1];
  const float* Wq   = (const float*)d_in[2];
  const float* bq   = (const float*)d_in[3];
  const float* Wk   = (const float*)d_in[4];
  const float* bk   = (const float*)d_in[5];
  const float* Wv   = (const float*)d_in[6];
  const float* bv   = (const float*)d_in[7];
  float* out = (float*)d_out;

  // workspace layout (~226 MB)
  f16* hs_h = (f16*)d_ws;                        // B*S*H
  f16* w_h  = hs_h + (size_t)B * S * H;          // 3*H*H concat
  f16* Qh   = w_h + (size_t)3 * H * H;           // B*S*H
  f16* Kh   = Qh + (size_t)B * S * H;            // B*S*H
  f16* Vt   = Kh + (size_t)B * S * H;            // B*H*S (transposed)
  f16* Sc   = Vt + (size_t)B * S * H;            // B*S*S f16

  const int castN = B * S * H / 4 + 3 * H * H / 4;
  cast_all<<<(castN + 255) / 256, 256, 0, stream>>>(hs, Wq, Wk, Wv, hs_h, w_h);

  dim3 blk(512);
  const float sscale = 0.088388347648318447f;  // 1/sqrt(HEAD_SIZE=128)

  // fused QKV: M=8192, N=6144, K=2048. grid (24,32), x fastest
  gemm_tn<0><<<dim3(24, 32), blk, 0, stream>>>(
      hs_h, w_h, Qh, Kh, Vt, bq, bk, bv, 1.f, H, H, H);

  // scores both batches: M=8192, N=4096, K=2048. grid (16,32)
  gemm_tn<2><<<dim3(16, 32), blk, 0, stream>>>(
      Qh, Kh, Sc, nullptr, nullptr, mask, nullptr, nullptr, sscale, H, H, H);

  softmax_f16<<<B * S, 256, 0, stream>>>(Sc);

  // PV both batches: M=8192, N=2048, K=4096. grid (8,32)
  gemm_tn<3><<<dim3(8, 32), blk, 0, stream>>>(
      Sc, Vt, out, nullptr, nullptr, nullptr, nullptr, nullptr, 1.f, S, S, S);
}